// Round 17
// baseline (94.708 us; speedup 1.0000x reference)
//
#include <hip/hip_runtime.h>
#include <cstddef>
#include <cstdint>

// Problem constants: T=2048, B=8, C=1024, H=16, K=31, P=15
constexpr int T_ = 2048;
constexpr int B_ = 8;
constexpr int C_ = 1024;
constexpr int H_ = 16;
constexpr int K_ = 31;
constexpr int P_ = 15;
constexpr int M_ = T_ * B_;   // 16384
constexpr int N_ = H_ * K_;   // 496
constexpr int NP = 512;       // padded N, slot layout n' = h*32 + k

typedef _Float16 f16x4 __attribute__((ext_vector_type(4)));
typedef _Float16 f16x8 __attribute__((ext_vector_type(8)));
typedef float f32x4 __attribute__((ext_vector_type(4)));

__device__ __forceinline__ void async_cp16(const void* g, void* l) {
    __builtin_amdgcn_global_load_lds(
        (const __attribute__((address_space(1))) void*)g,
        (__attribute__((address_space(3))) void*)l, 16, 0, 0);
}

// ---------------------------------------------------------------------------
// K0: W (496x1024 f32) -> Wh (512x1024 fp16, slot layout n'=h*32+k, k==31
// rows zero). ~1.5 us. X is NOT converted anywhere (gemm stages f32 X).
// ---------------------------------------------------------------------------
__global__ __launch_bounds__(256)
void cvt_w(const float* __restrict__ W, _Float16* __restrict__ Wh) {
    const int j = blockIdx.x * 256 + threadIdx.x;   // chunk id, 65536 total
    const int n = j >> 7, sp = j & 127;
    const int h = n >> 5, k = n & 31;
    f16x8 hv = {};
    if (k < 31) {
        const float* wp = W + (size_t)(h * 31 + k) * C_ + sp * 8;
        const float4 v0 = *(const float4*)(wp);
        const float4 v1 = *(const float4*)(wp + 4);
        hv[0] = (_Float16)v0.x; hv[1] = (_Float16)v0.y;
        hv[2] = (_Float16)v0.z; hv[3] = (_Float16)v0.w;
        hv[4] = (_Float16)v1.x; hv[5] = (_Float16)v1.y;
        hv[6] = (_Float16)v1.z; hv[7] = (_Float16)v1.w;
    }
    *(f16x8*)(Wh + (size_t)n * C_ + sp * 8) = hv;
}

// ---------------------------------------------------------------------------
// K1: GEMM -> raw f16 logits Lg. A staged as **f32 directly from X** via
// global_load_lds (no Xh!), converted f32->f16 at fragment read (VALU,
// hidden under MFMA). BM=BN=128, BK=64, 256 thr (4 waves 2x2, 64x64 tiles).
// A: 3-deep f32 buffers (32 KB each), counted vmcnt at prefetch distance 2.
// B: 2-deep f16 from Wh. LDS 128 KB -> 1 block/CU (pipeline is explicit,
// not occupancy-dependent). Swizzles: both-sides XOR involution; f32 rows
// have 16 chunks so XOR the low 3 bits, preserve bit 3 (kk).
// Epilogue: direct f16 stores (round-16 structure, softmax lives in dconv).
// ---------------------------------------------------------------------------
__global__ __launch_bounds__(256)
void gemm_logits(const float* __restrict__ X, const _Float16* __restrict__ Wh,
                 _Float16* __restrict__ Lg) {
    __shared__ float As[3][128 * 64];      // 3 x 32 KB (f32 A tiles)
    __shared__ _Float16 Bs[2][128 * 64];   // 2 x 16 KB

    const int tid = threadIdx.x;
    const int lane = tid & 63;
    const int w = tid >> 6;
    const int wm = (w >> 1) * 64;
    const int wn = (w & 1) * 64;
    const int col = lane & 15;
    const int g = lane >> 4;

    const int id = (int)blockIdx.x;
    const int bx = (id & 7) | ((id >> 5) << 3);
    const int by = (id >> 3) & 3;
    const int m0 = bx * 128;
    const int n0 = by * 128;

    // ---- A staging: 2048 chunks (128 rows x 16 f32-chunks), 8 per thread.
    // flat ci -> row r = ci>>4, pos cs = ci&15; source logical chunk
    // cl = (cs&8) | ((cs^r)&7)  (involution on low 3 bits).
    const float* asrc[8];
#pragma unroll
    for (int p = 0; p < 8; ++p) {
        const int ci = p * 256 + tid;
        const int r = ci >> 4, cs = ci & 15;
        const int cl = (cs & 8) | ((cs ^ r) & 7);
        asrc[p] = X + (size_t)(m0 + r) * C_ + cl * 4;
    }
    // ---- B staging: 1024 chunks (128 rows x 8 f16-chunks), 4 per thread.
    const _Float16* bsrc[4];
#pragma unroll
    for (int p = 0; p < 4; ++p) {
        const int ci = p * 256 + tid;
        const int r = ci >> 3, cs = ci & 7;
        const int cl = cs ^ (r & 7);
        bsrc[p] = Wh + (size_t)(n0 + r) * C_ + cl * 8;
    }

    f32x4 acc[4][4] = {};

#define ISSUE_A(k0, buf)                                                  \
    _Pragma("unroll")                                                     \
    for (int p = 0; p < 8; ++p) {                                         \
        const int ci = p * 256 + tid;                                     \
        async_cp16(asrc[p] + (k0), &As[buf][ci * 4]);                     \
    }
#define ISSUE_B(k0, buf)                                                  \
    _Pragma("unroll")                                                     \
    for (int p = 0; p < 4; ++p) {                                         \
        const int ci = p * 256 + tid;                                     \
        async_cp16(bsrc[p] + (k0), &Bs[buf][ci * 8]);                     \
    }

    // ---- prologue: A(0), B(0), A(1); drain A(0)+B(0), keep A(1) ----
    ISSUE_A(0, 0);
    ISSUE_B(0, 0);
    ISSUE_A(64, 1);
    asm volatile("s_waitcnt vmcnt(8)" ::: "memory");
    __builtin_amdgcn_s_barrier();
    __builtin_amdgcn_sched_barrier(0);

    for (int t = 0; t < 16; ++t) {
        const int ca = t % 3, cb = t & 1;
        if (t < 15) { ISSUE_B((t + 1) * 64, cb ^ 1); }
        if (t < 14) { ISSUE_A((t + 2) * 64, (t + 2) % 3); }

        // ---- compute k-step t: frag reads (f32 A -> cvt f16) + 32 MFMA ----
        f16x8 a[2][4], b[2][4];
#pragma unroll
        for (int kk = 0; kk < 2; ++kk) {
#pragma unroll
            for (int mf = 0; mf < 4; ++mf) {
                const int row = wm + mf * 16 + col;
                const int l0 = kk * 8 + 2 * g;          // logical f32 chunk
                const int p0 = (l0 & 8) | ((l0 ^ row) & 7);
                const int p1 = p0 ^ 1;                  // (l0|1) flips bit 0
                const f32x4 va = *(const f32x4*)&As[ca][row * 64 + p0 * 4];
                const f32x4 vb = *(const f32x4*)&As[ca][row * 64 + p1 * 4];
                f16x8 hv;
                hv[0] = (_Float16)va[0]; hv[1] = (_Float16)va[1];
                hv[2] = (_Float16)va[2]; hv[3] = (_Float16)va[3];
                hv[4] = (_Float16)vb[0]; hv[5] = (_Float16)vb[1];
                hv[6] = (_Float16)vb[2]; hv[7] = (_Float16)vb[3];
                a[kk][mf] = hv;
            }
#pragma unroll
            for (int nf = 0; nf < 4; ++nf) {
                const int row = wn + nf * 16 + col;
                const int c = ((kk << 2) | g) ^ (row & 7);
                b[kk][nf] = *(const f16x8*)&Bs[cb][row * 64 + c * 8];
            }
        }
#pragma unroll
        for (int kk = 0; kk < 2; ++kk)
#pragma unroll
            for (int nf = 0; nf < 4; ++nf)
#pragma unroll
                for (int mf = 0; mf < 4; ++mf)
                    acc[mf][nf] = __builtin_amdgcn_mfma_f32_16x16x32_f16(
                        a[kk][mf], b[kk][nf], acc[mf][nf], 0, 0, 0);

        // ---- counted wait: drain A(t+1)+B(t+1); keep A(t+2) in flight ----
        if (t < 14) {
            asm volatile("s_waitcnt vmcnt(8)" ::: "memory");
        } else {
            asm volatile("s_waitcnt vmcnt(0)" ::: "memory");
        }
        __builtin_amdgcn_s_barrier();
        __builtin_amdgcn_sched_barrier(0);
    }
#undef ISSUE_A
#undef ISSUE_B

    // ---- epilogue: raw f16 logits straight to global (slot layout) ----
    const int rb = g * 4;
#pragma unroll
    for (int nf = 0; nf < 4; ++nf) {
        const int nl = wn + nf * 16 + col;
#pragma unroll
        for (int mf = 0; mf < 4; ++mf) {
            const int row = wm + mf * 16 + rb;
#pragma unroll
            for (int r = 0; r < 4; ++r)
                Lg[(size_t)(m0 + row + r) * NP + n0 + nl] =
                    (_Float16)acc[mf][nf][r];
        }
    }
}

// ---------------------------------------------------------------------------
// K2: softmax + depthwise dynamic conv, x read as **f32 X** (L3-resident
// after the gemm pass; round-11-proven staging). Raw logits staged to
// ws16[64][40], softmaxed in-place (round-16), conv loop unchanged.
// ---------------------------------------------------------------------------
__global__ __launch_bounds__(256)
void dconv(const float* __restrict__ X, const _Float16* __restrict__ Lg,
           float* __restrict__ out) {
    __shared__ float xs[94][64];           // 24 KB
    __shared__ _Float16 ws16[64][40];      // 5 KB

    const int tid = threadIdx.x;
    const int t0 = blockIdx.x * 64;
    const int bh = (int)blockIdx.y;
    const int b = bh >> 4, h = bh & 15;

    // stage x window rows t0-15 .. t0+78 (swizzled 16B chunks, f32 direct)
    for (int task = tid; task < 94 * 16; task += 256) {
        const int r = task >> 4, sc = task & 15;
        const int tp = t0 + r - 15;
        f32x4 v = {};
        if (tp >= 0 && tp < T_)
            v = *(const f32x4*)(X + ((size_t)tp * B_ + b) * C_ + h * 64 + sc * 4);
        *(f32x4*)&xs[r][(sc ^ (r & 7)) * 4] = v;
    }
    // stage raw logits (one f16x8 per thread)
    {
        const int t = tid >> 2, kc = (tid & 3) * 8;
        const f16x8 wv =
            *(const f16x8*)(Lg + ((size_t)(t0 + t) * B_ + b) * NP + h * 32 + kc);
        *(f16x8*)&ws16[t][kc] = wv;
    }
    __syncthreads();

    // in-LDS softmax: one row per thread, tid < 64
    if (tid < 64) {
        float v[31];
        float mx = -1e30f;
#pragma unroll
        for (int k = 0; k < 31; ++k) {
            v[k] = (float)ws16[tid][k];
            mx = fmaxf(mx, v[k]);
        }
        float ssum = 0.f;
#pragma unroll
        for (int k = 0; k < 31; ++k) { v[k] = __expf(v[k] - mx); ssum += v[k]; }
        const float inv = 1.f / ssum;
#pragma unroll
        for (int k = 0; k < 31; ++k) ws16[tid][k] = (_Float16)(v[k] * inv);
    }
    __syncthreads();

    const int s = tid & 15;
    const int tg4 = (tid >> 4) * 4;
    f32x4 acc[4] = {};
    f32x4 wc[4];

#pragma unroll
    for (int rr = 0; rr < 34; ++rr) {
        const int r = tg4 + rr;
        const f32x4 xv = *(const f32x4*)&xs[r][(s ^ (r & 7)) * 4];
#pragma unroll
        for (int i = 0; i < 4; ++i) {
            const int k = rr - i;
            if (k < 0 || k > 30) continue;
            if ((k & 3) == 0) {
                const f16x4 wq = *(const f16x4*)&ws16[tg4 + i][k];
                wc[i][0] = (float)wq[0]; wc[i][1] = (float)wq[1];
                wc[i][2] = (float)wq[2]; wc[i][3] = (float)wq[3];
            }
            acc[i] += wc[i][k & 3] * xv;
        }
    }

#pragma unroll
    for (int i = 0; i < 4; ++i) {
        const int t = t0 + tg4 + i;
        *(f32x4*)(out + ((size_t)t * B_ + b) * C_ + h * 64 + s * 4) = acc[i];
    }
}

// ---------------------------------------------------------------------------
extern "C" void kernel_launch(void* const* d_in, const int* in_sizes, int n_in,
                              void* d_out, int out_size, void* d_ws,
                              size_t ws_size, hipStream_t stream) {
    const float* X = (const float*)d_in[0];
    const float* W = (const float*)d_in[1];
    float* out = (float*)d_out;

    // workspace: Wh (1 MiB) | Lg (16 MiB)
    _Float16* Wh = (_Float16*)d_ws;
    _Float16* Lg = (_Float16*)((char*)d_ws + (size_t)NP * C_ * 2);

    cvt_w<<<256, 256, 0, stream>>>(W, Wh);
    gemm_logits<<<512, 256, 0, stream>>>(X, Wh, Lg);
    dconv<<<dim3(T_ / 64, B_ * H_), 256, 0, stream>>>(X, Lg, out);
}

// Round 18
// 84.839 us; speedup vs baseline: 1.1163x; 1.1163x over previous
//
#include <hip/hip_runtime.h>
#include <cstddef>
#include <cstdint>

// Problem constants: T=2048, B=8, C=1024, H=16, K=31, P=15
constexpr int T_ = 2048;
constexpr int B_ = 8;
constexpr int C_ = 1024;
constexpr int H_ = 16;
constexpr int K_ = 31;
constexpr int P_ = 15;
constexpr int M_ = T_ * B_;   // 16384
constexpr int N_ = H_ * K_;   // 496
constexpr int NP = 512;       // padded N, slot layout n' = h*32 + k

typedef _Float16 f16x4 __attribute__((ext_vector_type(4)));
typedef _Float16 f16x8 __attribute__((ext_vector_type(8)));
typedef float f32x4 __attribute__((ext_vector_type(4)));

__device__ __forceinline__ void async_cp16(const void* g, void* l) {
    __builtin_amdgcn_global_load_lds(
        (const __attribute__((address_space(1))) void*)g,
        (__attribute__((address_space(3))) void*)l, 16, 0, 0);
}

// ---------------------------------------------------------------------------
// K0: fused convert. X -> Xh fp16; W -> Wh (512x1024 fp16, slot layout
// n' = h*32+k; k==31 rows zero, plain layout). Identical to round 16.
// ---------------------------------------------------------------------------
constexpr int XCH = M_ * C_ / 8;    // 2,097,152 f16x8 chunks
constexpr int WCH = NP * C_ / 8;    // 65,536

__global__ __launch_bounds__(256)
void cvt_inputs(const float* __restrict__ X, const float* __restrict__ W,
                _Float16* __restrict__ Xh, _Float16* __restrict__ Wh) {
    const int id = blockIdx.x * 256 + threadIdx.x;
    if (id < XCH) {
        const float4 v0 = *(const float4*)(X + (size_t)id * 8);
        const float4 v1 = *(const float4*)(X + (size_t)id * 8 + 4);
        f16x8 hv;
        hv[0] = (_Float16)v0.x; hv[1] = (_Float16)v0.y;
        hv[2] = (_Float16)v0.z; hv[3] = (_Float16)v0.w;
        hv[4] = (_Float16)v1.x; hv[5] = (_Float16)v1.y;
        hv[6] = (_Float16)v1.z; hv[7] = (_Float16)v1.w;
        *(f16x8*)(Xh + (size_t)id * 8) = hv;
    } else {
        const int j = id - XCH;
        const int n = j >> 7, sp = j & 127;
        const int h = n >> 5, k = n & 31;
        f16x8 hv = {};
        if (k < 31) {
            const float* wp = W + (size_t)(h * 31 + k) * C_ + sp * 8;
            const float4 v0 = *(const float4*)(wp);
            const float4 v1 = *(const float4*)(wp + 4);
            hv[0] = (_Float16)v0.x; hv[1] = (_Float16)v0.y;
            hv[2] = (_Float16)v0.z; hv[3] = (_Float16)v0.w;
            hv[4] = (_Float16)v1.x; hv[5] = (_Float16)v1.y;
            hv[6] = (_Float16)v1.z; hv[7] = (_Float16)v1.w;
        }
        *(f16x8*)(Wh + (size_t)n * C_ + sp * 8) = hv;
    }
}

// ---------------------------------------------------------------------------
// K1: GEMM -> raw f16 logits Lg. Round-16 A path (glds, 3-deep, counted
// vmcnt); NEW: B-fragments loaded DIRECTLY from Wh (1 MB, L2-resident) to
// VGPRs per k-step — no B LDS at all. Halves barrier-synced LDS traffic;
// LDS 48 KB. Issue order pinned (sched_barrier): B(t)[8] then A(t+2)[4] ->
// FIFO A(t+1),B(t),A(t+2); vmcnt(4) drains B(t)+A(t+1), keeps A(t+2).
// Epilogue: direct f16 logit stores (softmax lives in dconv).
// ---------------------------------------------------------------------------
__global__ __launch_bounds__(256, 2)
void gemm_logits(const _Float16* __restrict__ Xh,
                 const _Float16* __restrict__ Wh,
                 _Float16* __restrict__ Lg) {
    __shared__ _Float16 As[3][128 * 64];   // 48 KB total

    const int tid = threadIdx.x;
    const int lane = tid & 63;
    const int w = tid >> 6;
    const int wm = (w >> 1) * 64;
    const int wn = (w & 1) * 64;
    const int col = lane & 15;
    const int g = lane >> 4;

    const int id = (int)blockIdx.x;
    const int bx = (id & 7) | ((id >> 5) << 3);
    const int by = (id >> 3) & 3;
    const int m0 = bx * 128;
    const int n0 = by * 128;

    // A staging: 1024 chunks (128 rows x 8 f16-chunks), 4 per thread.
    const _Float16* asrc[4];
#pragma unroll
    for (int p = 0; p < 4; ++p) {
        const int ci = p * 256 + tid;
        const int r = ci >> 3, cs = ci & 7;
        const int cl = cs ^ (r & 7);
        asrc[p] = Xh + (size_t)(m0 + r) * C_ + cl * 8;
    }
    // B fragment base pointers: one per nf (per-lane row, k-chunk g).
    const _Float16* bfrag[4];
#pragma unroll
    for (int nf = 0; nf < 4; ++nf) {
        const int row = n0 + wn + nf * 16 + col;
        bfrag[nf] = Wh + (size_t)row * C_ + g * 8;
    }

    f32x4 acc[4][4] = {};

#define ISSUE_A(k0, buf)                                                  \
    _Pragma("unroll")                                                     \
    for (int p = 0; p < 4; ++p) {                                         \
        const int ci = p * 256 + tid;                                     \
        async_cp16(asrc[p] + (k0), &As[buf][ci * 8]);                     \
    }

    // ---- prologue: A(0), A(1); drain A(0), keep A(1) ----
    ISSUE_A(0, 0);
    ISSUE_A(64, 1);
    asm volatile("s_waitcnt vmcnt(4)" ::: "memory");
    __builtin_amdgcn_s_barrier();
    __builtin_amdgcn_sched_barrier(0);

    for (int t = 0; t < 16; ++t) {
        const int ca = t % 3;

        // ---- B-frag loads for step t (global -> VGPR, L2-resident) ----
        f16x8 b[2][4];
#pragma unroll
        for (int kk = 0; kk < 2; ++kk)
#pragma unroll
            for (int nf = 0; nf < 4; ++nf)
                b[kk][nf] = *(const f16x8*)(bfrag[nf] + t * 64 + kk * 32);
        __builtin_amdgcn_sched_barrier(0);   // pin: B(t) before A(t+2)

        // ---- A glds for step t+2 ----
        if (t < 14) { ISSUE_A((t + 2) * 64, (t + 2) % 3); }
        __builtin_amdgcn_sched_barrier(0);   // pin: A(t+2) after B(t)

        // ---- a-frag ds_reads (swizzled) ----
        f16x8 a[2][4];
#pragma unroll
        for (int kk = 0; kk < 2; ++kk)
#pragma unroll
            for (int mf = 0; mf < 4; ++mf) {
                const int row = wm + mf * 16 + col;
                const int c = ((kk << 2) | g) ^ (row & 7);
                a[kk][mf] = *(const f16x8*)&As[ca][row * 64 + c * 8];
            }

        // ---- drain B(t) + A(t+1); keep A(t+2) in flight ----
        if (t < 14) {
            asm volatile("s_waitcnt vmcnt(4) lgkmcnt(0)" ::: "memory");
        } else {
            asm volatile("s_waitcnt vmcnt(0) lgkmcnt(0)" ::: "memory");
        }
        __builtin_amdgcn_sched_barrier(0);

#pragma unroll
        for (int kk = 0; kk < 2; ++kk)
#pragma unroll
            for (int nf = 0; nf < 4; ++nf)
#pragma unroll
                for (int mf = 0; mf < 4; ++mf)
                    acc[mf][nf] = __builtin_amdgcn_mfma_f32_16x16x32_f16(
                        a[kk][mf], b[kk][nf], acc[mf][nf], 0, 0, 0);

        __builtin_amdgcn_s_barrier();
        __builtin_amdgcn_sched_barrier(0);
    }
#undef ISSUE_A

    // ---- epilogue: raw f16 logits straight to global (slot layout) ----
    const int rb = g * 4;
#pragma unroll
    for (int nf = 0; nf < 4; ++nf) {
        const int nl = wn + nf * 16 + col;
#pragma unroll
        for (int mf = 0; mf < 4; ++mf) {
            const int row = wm + mf * 16 + rb;
#pragma unroll
            for (int r = 0; r < 4; ++r)
                Lg[(size_t)(m0 + row + r) * NP + n0 + nl] =
                    (_Float16)acc[mf][nf][r];
        }
    }
}

// ---------------------------------------------------------------------------
// K2: softmax + depthwise dynamic conv. Identical to round 16.
// ---------------------------------------------------------------------------
__global__ __launch_bounds__(256)
void dconv(const _Float16* __restrict__ Xh, const _Float16* __restrict__ Lg,
           float* __restrict__ out) {
    __shared__ float xs[94][64];           // 24 KB
    __shared__ _Float16 ws16[64][40];      // 5 KB

    const int tid = threadIdx.x;
    const int t0 = blockIdx.x * 64;
    const int bh = (int)blockIdx.y;
    const int b = bh >> 4, h = bh & 15;

    for (int task = tid; task < 94 * 8; task += 256) {
        const int r = task >> 3, hc = task & 7;
        const int tp = t0 + r - 15;
        f16x8 v = {};
        if (tp >= 0 && tp < T_)
            v = *(const f16x8*)(Xh + ((size_t)tp * B_ + b) * C_ + h * 64 + hc * 8);
        f32x4 lo, hi;
        lo[0] = (float)v[0]; lo[1] = (float)v[1];
        lo[2] = (float)v[2]; lo[3] = (float)v[3];
        hi[0] = (float)v[4]; hi[1] = (float)v[5];
        hi[2] = (float)v[6]; hi[3] = (float)v[7];
        const int c0 = (2 * hc) ^ (r & 7), c1 = (2 * hc + 1) ^ (r & 7);
        *(f32x4*)&xs[r][c0 * 4] = lo;
        *(f32x4*)&xs[r][c1 * 4] = hi;
    }
    {
        const int t = tid >> 2, kc = (tid & 3) * 8;
        const f16x8 wv =
            *(const f16x8*)(Lg + ((size_t)(t0 + t) * B_ + b) * NP + h * 32 + kc);
        *(f16x8*)&ws16[t][kc] = wv;
    }
    __syncthreads();

    if (tid < 64) {
        float v[31];
        float mx = -1e30f;
#pragma unroll
        for (int k = 0; k < 31; ++k) {
            v[k] = (float)ws16[tid][k];
            mx = fmaxf(mx, v[k]);
        }
        float ssum = 0.f;
#pragma unroll
        for (int k = 0; k < 31; ++k) { v[k] = __expf(v[k] - mx); ssum += v[k]; }
        const float inv = 1.f / ssum;
#pragma unroll
        for (int k = 0; k < 31; ++k) ws16[tid][k] = (_Float16)(v[k] * inv);
    }
    __syncthreads();

    const int s = tid & 15;
    const int tg4 = (tid >> 4) * 4;
    f32x4 acc[4] = {};
    f32x4 wc[4];

#pragma unroll
    for (int rr = 0; rr < 34; ++rr) {
        const int r = tg4 + rr;
        const f32x4 xv = *(const f32x4*)&xs[r][(s ^ (r & 7)) * 4];
#pragma unroll
        for (int i = 0; i < 4; ++i) {
            const int k = rr - i;
            if (k < 0 || k > 30) continue;
            if ((k & 3) == 0) {
                const f16x4 wq = *(const f16x4*)&ws16[tg4 + i][k];
                wc[i][0] = (float)wq[0]; wc[i][1] = (float)wq[1];
                wc[i][2] = (float)wq[2]; wc[i][3] = (float)wq[3];
            }
            acc[i] += wc[i][k & 3] * xv;
        }
    }

#pragma unroll
    for (int i = 0; i < 4; ++i) {
        const int t = t0 + tg4 + i;
        *(f32x4*)(out + ((size_t)t * B_ + b) * C_ + h * 64 + s * 4) = acc[i];
    }
}

// ---------------------------------------------------------------------------
extern "C" void kernel_launch(void* const* d_in, const int* in_sizes, int n_in,
                              void* d_out, int out_size, void* d_ws,
                              size_t ws_size, hipStream_t stream) {
    const float* X = (const float*)d_in[0];
    const float* W = (const float*)d_in[1];
    float* out = (float*)d_out;

    // workspace: Wh (1 MiB) | Lg (16 MiB) | Xh (32 MiB)  = 49 MiB
    _Float16* Wh = (_Float16*)d_ws;
    _Float16* Lg = (_Float16*)((char*)d_ws + (size_t)NP * C_ * 2);
    _Float16* Xh = (_Float16*)((char*)d_ws + (size_t)NP * C_ * 2 +
                               (size_t)M_ * NP * 2);

    cvt_inputs<<<(XCH + WCH) / 256, 256, 0, stream>>>(X, W, Xh, Wh);
    gemm_logits<<<512, 256, 0, stream>>>(Xh, Wh, Lg);
    dconv<<<dim3(T_ / 64, B_ * H_), 256, 0, stream>>>(Xh, Lg, out);
}

// Round 19
// 79.482 us; speedup vs baseline: 1.1916x; 1.0674x over previous
//
#include <hip/hip_runtime.h>
#include <cstddef>
#include <cstdint>

// Problem constants: T=2048, B=8, C=1024, H=16, K=31, P=15
constexpr int T_ = 2048;
constexpr int B_ = 8;
constexpr int C_ = 1024;
constexpr int H_ = 16;
constexpr int K_ = 31;
constexpr int P_ = 15;
constexpr int M_ = T_ * B_;   // 16384
constexpr int N_ = H_ * K_;   // 496
constexpr int NP = 512;       // padded N, slot layout n' = h*32 + k

typedef _Float16 f16x4 __attribute__((ext_vector_type(4)));
typedef _Float16 f16x8 __attribute__((ext_vector_type(8)));
typedef float f32x4 __attribute__((ext_vector_type(4)));

__device__ __forceinline__ void async_cp16(const void* g, void* l) {
    __builtin_amdgcn_global_load_lds(
        (const __attribute__((address_space(1))) void*)g,
        (__attribute__((address_space(3))) void*)l, 16, 0, 0);
}

// ---------------------------------------------------------------------------
// K0: W (496x1024 f32) -> Wh (512x1024 fp16, slot layout n'=h*32+k, k==31
// rows zero). ~1.5 us. X is never converted (gemm stages f32 X directly).
// ---------------------------------------------------------------------------
__global__ __launch_bounds__(256)
void cvt_w(const float* __restrict__ W, _Float16* __restrict__ Wh) {
    const int j = blockIdx.x * 256 + threadIdx.x;   // chunk id, 65536 total
    const int n = j >> 7, sp = j & 127;
    const int h = n >> 5, k = n & 31;
    f16x8 hv = {};
    if (k < 31) {
        const float* wp = W + (size_t)(h * 31 + k) * C_ + sp * 8;
        const float4 v0 = *(const float4*)(wp);
        const float4 v1 = *(const float4*)(wp + 4);
        hv[0] = (_Float16)v0.x; hv[1] = (_Float16)v0.y;
        hv[2] = (_Float16)v0.z; hv[3] = (_Float16)v0.w;
        hv[4] = (_Float16)v1.x; hv[5] = (_Float16)v1.y;
        hv[6] = (_Float16)v1.z; hv[7] = (_Float16)v1.w;
    }
    *(f16x8*)(Wh + (size_t)n * C_ + sp * 8) = hv;
}

// ---------------------------------------------------------------------------
// K1: GEMM -> raw f16 logits Lg. A staged as f32 DIRECTLY from X via
// global_load_lds at BK=32 (f32 tile = 16 KB, 3-deep = 48 KB); B f16 from
// Wh, 3-deep (8 KB each). Total 72 KB -> 2 blocks/CU (the property r17
// lost). True prefetch distance 2 for both operands: step t issues
// {B(t+2), A(t+2)} [6 loads/thread]; end-of-step vmcnt(6) drains (t+1)'s
// set, keeps (t+2)'s in flight. f32->f16 at fragment read (VALU, overlaps
// MFMA). 4 waves 2x2, wave tile 64x64, 16 MFMA/step, 32 steps.
// Epilogue: direct f16 logit stores (softmax lives in dconv).
// ---------------------------------------------------------------------------
__global__ __launch_bounds__(256)
void gemm_logits(const float* __restrict__ X, const _Float16* __restrict__ Wh,
                 _Float16* __restrict__ Lg) {
    __shared__ float As[3][128 * 32];      // 3 x 16 KB (f32 A tiles)
    __shared__ _Float16 Bs[3][128 * 32];   // 3 x 8 KB

    const int tid = threadIdx.x;
    const int lane = tid & 63;
    const int w = tid >> 6;
    const int wm = (w >> 1) * 64;
    const int wn = (w & 1) * 64;
    const int col = lane & 15;
    const int g = lane >> 4;         // k-chunk 0..3 (8 halves / 2 f32-chunks)

    const int id = (int)blockIdx.x;
    const int bx = (id & 7) | ((id >> 5) << 3);
    const int by = (id >> 3) & 3;
    const int m0 = bx * 128;
    const int n0 = by * 128;

    // ---- A staging: 1024 chunks (128 rows x 8 f32-chunks of 16B), 4/thr.
    // flat ci -> row r = ci>>3, pos cs = ci&7; source logical chunk
    // cl = cs ^ (r&7) (involution).
    const float* asrc[4];
#pragma unroll
    for (int p = 0; p < 4; ++p) {
        const int ci = p * 256 + tid;
        const int r = ci >> 3, cs = ci & 7;
        const int cl = cs ^ (r & 7);
        asrc[p] = X + (size_t)(m0 + r) * C_ + cl * 4;
    }
    // ---- B staging: 512 chunks (128 rows x 4 f16-chunks), 2/thread.
    const _Float16* bsrc[2];
#pragma unroll
    for (int p = 0; p < 2; ++p) {
        const int ci = p * 256 + tid;
        const int r = ci >> 2, cs = ci & 3;
        const int cl = cs ^ (r & 3);
        bsrc[p] = Wh + (size_t)(n0 + r) * C_ + cl * 8;
    }

    f32x4 acc[4][4] = {};

#define ISSUE(t_, buf_)                                                   \
    _Pragma("unroll")                                                     \
    for (int p = 0; p < 2; ++p) {                                         \
        const int ci = p * 256 + tid;                                     \
        async_cp16(bsrc[p] + (t_) * 32, &Bs[buf_][ci * 8]);               \
    }                                                                     \
    _Pragma("unroll")                                                     \
    for (int p = 0; p < 4; ++p) {                                         \
        const int ci = p * 256 + tid;                                     \
        async_cp16(asrc[p] + (t_) * 32, &As[buf_][ci * 4]);               \
    }

    // ---- prologue: issue steps 0,1; drain step 0, keep step 1 in flight ----
    ISSUE(0, 0);
    ISSUE(1, 1);
    asm volatile("s_waitcnt vmcnt(6)" ::: "memory");
    __builtin_amdgcn_s_barrier();
    __builtin_amdgcn_sched_barrier(0);

    for (int t = 0; t < 32; ++t) {
        const int cur = t % 3;
        if (t < 30) { ISSUE(t + 2, (t + 2) % 3); }

        // ---- compute k-step t: frag reads (f32 A -> cvt f16) + 16 MFMA ----
        f16x8 a[4], b[4];
#pragma unroll
        for (int mf = 0; mf < 4; ++mf) {
            const int row = wm + mf * 16 + col;
            const int p0 = (2 * g) ^ (row & 7);
            const int p1 = p0 ^ 1;               // (2g+1)^(row&7)
            const f32x4 va = *(const f32x4*)&As[cur][row * 32 + p0 * 4];
            const f32x4 vb = *(const f32x4*)&As[cur][row * 32 + p1 * 4];
            f16x8 hv;
            hv[0] = (_Float16)va[0]; hv[1] = (_Float16)va[1];
            hv[2] = (_Float16)va[2]; hv[3] = (_Float16)va[3];
            hv[4] = (_Float16)vb[0]; hv[5] = (_Float16)vb[1];
            hv[6] = (_Float16)vb[2]; hv[7] = (_Float16)vb[3];
            a[mf] = hv;
        }
#pragma unroll
        for (int nf = 0; nf < 4; ++nf) {
            const int row = wn + nf * 16 + col;
            const int c = g ^ (row & 3);
            b[nf] = *(const f16x8*)&Bs[cur][row * 32 + c * 8];
        }
#pragma unroll
        for (int nf = 0; nf < 4; ++nf)
#pragma unroll
            for (int mf = 0; mf < 4; ++mf)
                acc[mf][nf] = __builtin_amdgcn_mfma_f32_16x16x32_f16(
                    a[mf], b[nf], acc[mf][nf], 0, 0, 0);

        // ---- counted wait: drain (t+1)'s set, keep (t+2)'s in flight ----
        if (t < 30) {
            asm volatile("s_waitcnt vmcnt(6)" ::: "memory");
        } else {
            asm volatile("s_waitcnt vmcnt(0)" ::: "memory");
        }
        __builtin_amdgcn_s_barrier();
        __builtin_amdgcn_sched_barrier(0);
    }
#undef ISSUE

    // ---- epilogue: raw f16 logits straight to global (slot layout) ----
    const int rb = g * 4;
#pragma unroll
    for (int nf = 0; nf < 4; ++nf) {
        const int nl = wn + nf * 16 + col;
#pragma unroll
        for (int mf = 0; mf < 4; ++mf) {
            const int row = wm + mf * 16 + rb;
#pragma unroll
            for (int r = 0; r < 4; ++r)
                Lg[(size_t)(m0 + row + r) * NP + n0 + nl] =
                    (_Float16)acc[mf][nf][r];
        }
    }
}

// ---------------------------------------------------------------------------
// K2: softmax + depthwise dynamic conv, x read as f32 X (L3-resident after
// the gemm pass; round-11-proven staging). Raw logits staged to ws16[64][40],
// softmaxed in-place (round-16), conv loop unchanged.
// ---------------------------------------------------------------------------
__global__ __launch_bounds__(256)
void dconv(const float* __restrict__ X, const _Float16* __restrict__ Lg,
           float* __restrict__ out) {
    __shared__ float xs[94][64];           // 24 KB
    __shared__ _Float16 ws16[64][40];      // 5 KB

    const int tid = threadIdx.x;
    const int t0 = blockIdx.x * 64;
    const int bh = (int)blockIdx.y;
    const int b = bh >> 4, h = bh & 15;

    // stage x window rows t0-15 .. t0+78 (swizzled 16B chunks, f32 direct)
    for (int task = tid; task < 94 * 16; task += 256) {
        const int r = task >> 4, sc = task & 15;
        const int tp = t0 + r - 15;
        f32x4 v = {};
        if (tp >= 0 && tp < T_)
            v = *(const f32x4*)(X + ((size_t)tp * B_ + b) * C_ + h * 64 + sc * 4);
        *(f32x4*)&xs[r][(sc ^ (r & 7)) * 4] = v;
    }
    // stage raw logits (one f16x8 per thread)
    {
        const int t = tid >> 2, kc = (tid & 3) * 8;
        const f16x8 wv =
            *(const f16x8*)(Lg + ((size_t)(t0 + t) * B_ + b) * NP + h * 32 + kc);
        *(f16x8*)&ws16[t][kc] = wv;
    }
    __syncthreads();

    // in-LDS softmax: one row per thread, tid < 64
    if (tid < 64) {
        float v[31];
        float mx = -1e30f;
#pragma unroll
        for (int k = 0; k < 31; ++k) {
            v[k] = (float)ws16[tid][k];
            mx = fmaxf(mx, v[k]);
        }
        float ssum = 0.f;
#pragma unroll
        for (int k = 0; k < 31; ++k) { v[k] = __expf(v[k] - mx); ssum += v[k]; }
        const float inv = 1.f / ssum;
#pragma unroll
        for (int k = 0; k < 31; ++k) ws16[tid][k] = (_Float16)(v[k] * inv);
    }
    __syncthreads();

    const int s = tid & 15;
    const int tg4 = (tid >> 4) * 4;
    f32x4 acc[4] = {};
    f32x4 wc[4];

#pragma unroll
    for (int rr = 0; rr < 34; ++rr) {
        const int r = tg4 + rr;
        const f32x4 xv = *(const f32x4*)&xs[r][(s ^ (r & 7)) * 4];
#pragma unroll
        for (int i = 0; i < 4; ++i) {
            const int k = rr - i;
            if (k < 0 || k > 30) continue;
            if ((k & 3) == 0) {
                const f16x4 wq = *(const f16x4*)&ws16[tg4 + i][k];
                wc[i][0] = (float)wq[0]; wc[i][1] = (float)wq[1];
                wc[i][2] = (float)wq[2]; wc[i][3] = (float)wq[3];
            }
            acc[i] += wc[i][k & 3] * xv;
        }
    }

#pragma unroll
    for (int i = 0; i < 4; ++i) {
        const int t = t0 + tg4 + i;
        *(f32x4*)(out + ((size_t)t * B_ + b) * C_ + h * 64 + s * 4) = acc[i];
    }
}

// ---------------------------------------------------------------------------
extern "C" void kernel_launch(void* const* d_in, const int* in_sizes, int n_in,
                              void* d_out, int out_size, void* d_ws,
                              size_t ws_size, hipStream_t stream) {
    const float* X = (const float*)d_in[0];
    const float* W = (const float*)d_in[1];
    float* out = (float*)d_out;

    // workspace: Wh (1 MiB) | Lg (16 MiB)
    _Float16* Wh = (_Float16*)d_ws;
    _Float16* Lg = (_Float16*)((char*)d_ws + (size_t)NP * C_ * 2);

    cvt_w<<<256, 256, 0, stream>>>(W, Wh);
    gemm_logits<<<512, 256, 0, stream>>>(X, Wh, Lg);
    dconv<<<dim3(T_ / 64, B_ * H_), 256, 0, stream>>>(X, Lg, out);
}

// Round 20
// 70.201 us; speedup vs baseline: 1.3491x; 1.1322x over previous
//
#include <hip/hip_runtime.h>
#include <cstddef>
#include <cstdint>

// Problem constants: T=2048, B=8, C=1024, H=16, K=31, P=15
constexpr int T_ = 2048;
constexpr int B_ = 8;
constexpr int C_ = 1024;
constexpr int H_ = 16;
constexpr int K_ = 31;
constexpr int P_ = 15;
constexpr int M_ = T_ * B_;   // 16384
constexpr int N_ = H_ * K_;   // 496
constexpr int NP = 512;       // padded N, slot layout n' = h*32 + k

typedef _Float16 f16x4 __attribute__((ext_vector_type(4)));
typedef _Float16 f16x8 __attribute__((ext_vector_type(8)));
typedef float f32x4 __attribute__((ext_vector_type(4)));

__device__ __forceinline__ void async_cp16(const void* g, void* l) {
    __builtin_amdgcn_global_load_lds(
        (const __attribute__((address_space(1))) void*)g,
        (__attribute__((address_space(3))) void*)l, 16, 0, 0);
}

// ---------------------------------------------------------------------------
// K0: fused convert. X -> Xh fp16; W -> Wh (512x1024 fp16, slot layout
// n' = h*32+k; k==31 rows zero). Runs at ~85% HBM BW (floor).
// ---------------------------------------------------------------------------
constexpr int XCH = M_ * C_ / 8;    // 2,097,152 f16x8 chunks
constexpr int WCH = NP * C_ / 8;    // 65,536

__global__ __launch_bounds__(256)
void cvt_inputs(const float* __restrict__ X, const float* __restrict__ W,
                _Float16* __restrict__ Xh, _Float16* __restrict__ Wh) {
    const int id = blockIdx.x * 256 + threadIdx.x;
    if (id < XCH) {
        const float4 v0 = *(const float4*)(X + (size_t)id * 8);
        const float4 v1 = *(const float4*)(X + (size_t)id * 8 + 4);
        f16x8 hv;
        hv[0] = (_Float16)v0.x; hv[1] = (_Float16)v0.y;
        hv[2] = (_Float16)v0.z; hv[3] = (_Float16)v0.w;
        hv[4] = (_Float16)v1.x; hv[5] = (_Float16)v1.y;
        hv[6] = (_Float16)v1.z; hv[7] = (_Float16)v1.w;
        *(f16x8*)(Xh + (size_t)id * 8) = hv;
    } else {
        const int j = id - XCH;
        const int n = j >> 7, sp = j & 127;
        const int h = n >> 5, k = n & 31;
        f16x8 hv = {};
        if (k < 31) {
            const float* wp = W + (size_t)(h * 31 + k) * C_ + sp * 8;
            const float4 v0 = *(const float4*)(wp);
            const float4 v1 = *(const float4*)(wp + 4);
            hv[0] = (_Float16)v0.x; hv[1] = (_Float16)v0.y;
            hv[2] = (_Float16)v0.z; hv[3] = (_Float16)v0.w;
            hv[4] = (_Float16)v1.x; hv[5] = (_Float16)v1.y;
            hv[6] = (_Float16)v1.z; hv[7] = (_Float16)v1.w;
        }
        *(f16x8*)(Wh + (size_t)n * C_ + sp * 8) = hv;
    }
}

// ---------------------------------------------------------------------------
// K1: GEMM -> raw f16 logits Lg (slot layout). Counted-vmcnt pipeline
// (A 3-deep, B 2-deep, BK=64, 80 KB LDS, 2 blocks/CU). Epilogue: direct
// f16 stores of acc (no LDS overlay, no barriers — softmax lives in dconv).
// Proven best: round 16, 70.1 us total.
// ---------------------------------------------------------------------------
__global__ __launch_bounds__(256)
void gemm_logits(const _Float16* __restrict__ Xh,
                 const _Float16* __restrict__ Wh,
                 _Float16* __restrict__ Lg) {
    __shared__ _Float16 As[3][128 * 64];   // 48 KB
    __shared__ _Float16 Bs[2][128 * 64];   // 32 KB

    const int tid = threadIdx.x;
    const int lane = tid & 63;
    const int w = tid >> 6;
    const int wm = (w >> 1) * 64;
    const int wn = (w & 1) * 64;
    const int col = lane & 15;
    const int g = lane >> 4;

    const int id = (int)blockIdx.x;
    const int bx = (id & 7) | ((id >> 5) << 3);
    const int by = (id >> 3) & 3;
    const int m0 = bx * 128;
    const int n0 = by * 128;

    const _Float16* asrc[4];
    const _Float16* bsrc[4];
#pragma unroll
    for (int p = 0; p < 4; ++p) {
        const int ci = p * 256 + tid;
        const int r = ci >> 3, cs = ci & 7;
        const int cl = cs ^ (r & 7);
        asrc[p] = Xh + (size_t)(m0 + r) * C_ + cl * 8;
        bsrc[p] = Wh + (size_t)(n0 + r) * C_ + cl * 8;
    }

    f32x4 acc[4][4] = {};

#pragma unroll
    for (int p = 0; p < 4; ++p) {
        const int ci = p * 256 + tid;
        async_cp16(asrc[p], &As[0][ci * 8]);
    }
#pragma unroll
    for (int p = 0; p < 4; ++p) {
        const int ci = p * 256 + tid;
        async_cp16(bsrc[p], &Bs[0][ci * 8]);
    }
#pragma unroll
    for (int p = 0; p < 4; ++p) {
        const int ci = p * 256 + tid;
        async_cp16(asrc[p] + 64, &As[1][ci * 8]);
    }
    asm volatile("s_waitcnt vmcnt(4)" ::: "memory");
    __builtin_amdgcn_s_barrier();
    __builtin_amdgcn_sched_barrier(0);

    for (int t = 0; t < 16; ++t) {
        const int ca = t % 3, cb = t & 1;
        if (t < 15) {
            const int k1 = (t + 1) * 64;
#pragma unroll
            for (int p = 0; p < 4; ++p) {
                const int ci = p * 256 + tid;
                async_cp16(bsrc[p] + k1, &Bs[cb ^ 1][ci * 8]);
            }
        }
        if (t < 14) {
            const int k2 = (t + 2) * 64;
            const int ca2 = (t + 2) % 3;
#pragma unroll
            for (int p = 0; p < 4; ++p) {
                const int ci = p * 256 + tid;
                async_cp16(asrc[p] + k2, &As[ca2][ci * 8]);
            }
        }

        f16x8 a[2][4], b[2][4];
#pragma unroll
        for (int kk = 0; kk < 2; ++kk) {
#pragma unroll
            for (int mf = 0; mf < 4; ++mf) {
                const int row = wm + mf * 16 + col;
                const int c = ((kk << 2) | g) ^ (row & 7);
                a[kk][mf] = *(const f16x8*)&As[ca][row * 64 + c * 8];
            }
#pragma unroll
            for (int nf = 0; nf < 4; ++nf) {
                const int row = wn + nf * 16 + col;
                const int c = ((kk << 2) | g) ^ (row & 7);
                b[kk][nf] = *(const f16x8*)&Bs[cb][row * 64 + c * 8];
            }
        }
#pragma unroll
        for (int kk = 0; kk < 2; ++kk)
#pragma unroll
            for (int nf = 0; nf < 4; ++nf)
#pragma unroll
                for (int mf = 0; mf < 4; ++mf)
                    acc[mf][nf] = __builtin_amdgcn_mfma_f32_16x16x32_f16(
                        a[kk][mf], b[kk][nf], acc[mf][nf], 0, 0, 0);

        if (t < 14) {
            asm volatile("s_waitcnt vmcnt(4)" ::: "memory");
        } else {
            asm volatile("s_waitcnt vmcnt(0)" ::: "memory");
        }
        __builtin_amdgcn_s_barrier();
        __builtin_amdgcn_sched_barrier(0);
    }

    // ---- epilogue: raw f16 logits straight to global (slot layout) ----
    const int rb = g * 4;
#pragma unroll
    for (int nf = 0; nf < 4; ++nf) {
        const int nl = wn + nf * 16 + col;
#pragma unroll
        for (int mf = 0; mf < 4; ++mf) {
            const int row = wm + mf * 16 + rb;
#pragma unroll
            for (int r = 0; r < 4; ++r)
                Lg[(size_t)(m0 + row + r) * NP + n0 + nl] =
                    (_Float16)acc[mf][nf][r];
        }
    }
}

// ---------------------------------------------------------------------------
// K2: softmax + depthwise dynamic conv. Stages raw logits into ws16[64][40]
// f16, softmaxes in-place (1 wave, hidden under memory phase at high
// occupancy), conv weights converted f16->f32 at use.
// ---------------------------------------------------------------------------
__global__ __launch_bounds__(256)
void dconv(const _Float16* __restrict__ Xh, const _Float16* __restrict__ Lg,
           float* __restrict__ out) {
    __shared__ float xs[94][64];           // 24 KB
    __shared__ _Float16 ws16[64][40];      // 5 KB

    const int tid = threadIdx.x;
    const int t0 = blockIdx.x * 64;
    const int bh = (int)blockIdx.y;
    const int b = bh >> 4, h = bh & 15;

    // stage x window rows t0-15 .. t0+78: f16x8 loads -> 2 swizzled f32x4
    for (int task = tid; task < 94 * 8; task += 256) {
        const int r = task >> 3, hc = task & 7;
        const int tp = t0 + r - 15;
        f16x8 v = {};
        if (tp >= 0 && tp < T_)
            v = *(const f16x8*)(Xh + ((size_t)tp * B_ + b) * C_ + h * 64 + hc * 8);
        f32x4 lo, hi;
        lo[0] = (float)v[0]; lo[1] = (float)v[1];
        lo[2] = (float)v[2]; lo[3] = (float)v[3];
        hi[0] = (float)v[4]; hi[1] = (float)v[5];
        hi[2] = (float)v[6]; hi[3] = (float)v[7];
        const int c0 = (2 * hc) ^ (r & 7), c1 = (2 * hc + 1) ^ (r & 7);
        *(f32x4*)&xs[r][c0 * 4] = lo;
        *(f32x4*)&xs[r][c1 * 4] = hi;
    }
    // stage raw logits (f16 copy, one f16x8 per thread)
    {
        const int t = tid >> 2, kc = (tid & 3) * 8;
        const f16x8 wv =
            *(const f16x8*)(Lg + ((size_t)(t0 + t) * B_ + b) * NP + h * 32 + kc);
        *(f16x8*)&ws16[t][kc] = wv;
    }
    __syncthreads();

    // in-LDS softmax: one row per thread, tid < 64
    if (tid < 64) {
        float v[31];
        float mx = -1e30f;
#pragma unroll
        for (int k = 0; k < 31; ++k) {
            v[k] = (float)ws16[tid][k];
            mx = fmaxf(mx, v[k]);
        }
        float ssum = 0.f;
#pragma unroll
        for (int k = 0; k < 31; ++k) { v[k] = __expf(v[k] - mx); ssum += v[k]; }
        const float inv = 1.f / ssum;
#pragma unroll
        for (int k = 0; k < 31; ++k) ws16[tid][k] = (_Float16)(v[k] * inv);
    }
    __syncthreads();

    const int s = tid & 15;
    const int tg4 = (tid >> 4) * 4;
    f32x4 acc[4] = {};
    f32x4 wc[4];

#pragma unroll
    for (int rr = 0; rr < 34; ++rr) {
        const int r = tg4 + rr;
        const f32x4 xv = *(const f32x4*)&xs[r][(s ^ (r & 7)) * 4];
#pragma unroll
        for (int i = 0; i < 4; ++i) {
            const int k = rr - i;
            if (k < 0 || k > 30) continue;
            if ((k & 3) == 0) {
                const f16x4 wq = *(const f16x4*)&ws16[tg4 + i][k];
                wc[i][0] = (float)wq[0]; wc[i][1] = (float)wq[1];
                wc[i][2] = (float)wq[2]; wc[i][3] = (float)wq[3];
            }
            acc[i] += wc[i][k & 3] * xv;
        }
    }

#pragma unroll
    for (int i = 0; i < 4; ++i) {
        const int t = t0 + tg4 + i;
        *(f32x4*)(out + ((size_t)t * B_ + b) * C_ + h * 64 + s * 4) = acc[i];
    }
}

// ---------------------------------------------------------------------------
extern "C" void kernel_launch(void* const* d_in, const int* in_sizes, int n_in,
                              void* d_out, int out_size, void* d_ws,
                              size_t ws_size, hipStream_t stream) {
    const float* X = (const float*)d_in[0];
    const float* W = (const float*)d_in[1];
    float* out = (float*)d_out;

    // workspace: Wh (1 MiB) | Lg (16 MiB) | Xh (32 MiB)  = 49 MiB
    _Float16* Wh = (_Float16*)d_ws;
    _Float16* Lg = (_Float16*)((char*)d_ws + (size_t)NP * C_ * 2);
    _Float16* Xh = (_Float16*)((char*)d_ws + (size_t)NP * C_ * 2 +
                               (size_t)M_ * NP * 2);

    cvt_inputs<<<(XCH + WCH) / 256, 256, 0, stream>>>(X, W, Xh, Wh);
    gemm_logits<<<512, 256, 0, stream>>>(Xh, Wh, Lg);
    dconv<<<dim3(T_ / 64, B_ * H_), 256, 0, stream>>>(Xh, Lg, out);
}